// Round 4
// baseline (358.475 us; speedup 1.0000x reference)
//
#include <hip/hip_runtime.h>
#include <cmath>

// Problem constants
#define BB 16384
#define DD 256
#define UU 256
#define TT 32
#define MM 64

// ws layout (float offsets)
#define WS_ALPHA 0
#define WS_BETA  16384
#define WS_M1    32768
#define WS_M2    33024
#define WS_V1    33280
#define WS_V2    34304
#define WS_PART1 35328
#define WS_PART2 68096
#define WS_BF16_BYTE 403456   // = 100864 floats * 4
// bf16 region (shorts):
//   Ahi[16 kc][16384 m][32], Alo same (16.78 MB each)
//   Bg [8 nb][16 kc][10240]  (2.62 MB)

typedef short bf16x8 __attribute__((ext_vector_type(8)));
typedef float f32x4  __attribute__((ext_vector_type(4)));

__device__ __forceinline__ float hsig(float x) {
    return fminf(1.0f, fmaxf(0.0f, fmaf(0.2f, x, 0.5f)));
}
__device__ __forceinline__ short f2bf(float x) {
    unsigned u = __float_as_uint(x);
    unsigned r = (u + 0x7fffu + ((u >> 16) & 1u)) >> 16;
    return (short)r;
}
__device__ __forceinline__ float bf2f(short h) {
    return __uint_as_float(((unsigned)(unsigned short)h) << 16);
}

// ---- D1: fused prep: conv_a | conv_b | coef | colsum-partials ----
__global__ void k_prep(const float* __restrict__ inputs, const float* __restrict__ h1,
                       const float* __restrict__ h2,
                       const int* __restrict__ neighbors, const int* __restrict__ mapping,
                       const int* __restrict__ revmap, const int* __restrict__ timep,
                       const float* __restrict__ W, const float* __restrict__ U,
                       const float* __restrict__ Un,
                       short* __restrict__ Ahi, short* __restrict__ Alo,
                       short* __restrict__ Bg,
                       float* __restrict__ alpha, float* __restrict__ beta,
                       float* __restrict__ part1, float* __restrict__ part2) {
    int blk = blockIdx.x;
    int tid = threadIdx.x;
    if (blk < 4096) {
        // conv_a: A=[inputs|h_tm1] -> hi/lo bf16, fragment-ordered
        // A[kc][m][q*8+j] = A_f32[m][kc*32 + q*4 + (j&3) + 16*(j>>2)]
        int q = tid & 3;
        int m = (blk & 255) * 64 + (tid >> 2);
        int kc = blk >> 8;
        int k0 = kc * 32 + q * 4;
        const float* src = (k0 < 256) ? (inputs + m * 256 + k0) : (h1 + m * 256 + k0 - 256);
        float4 x0 = *(const float4*)(src);
        float4 x1 = *(const float4*)(src + 16);
        float xs[8] = {x0.x, x0.y, x0.z, x0.w, x1.x, x1.y, x1.z, x1.w};
        bf16x8 hv, lv;
        #pragma unroll
        for (int j = 0; j < 8; j++) {
            short h = f2bf(xs[j]);
            hv[j] = h;
            lv[j] = f2bf(xs[j] - bf2f(h));
        }
        long doff = ((long)kc * 16384 + m) * 32 + q * 8;
        *(bf16x8*)(Ahi + doff) = hv;
        *(bf16x8*)(Alo + doff) = lv;
    } else if (blk < 4416) {
        // conv_b: B virtual 512x1280 gate-interleaved -> swizzled LDS image
        int t = (blk - 4096) * 256 + tid;
        int q = t & 3;
        int r = t >> 2;
        int nl = r % 160;
        int r2 = r / 160;
        int kc = r2 & 15;
        int nb = r2 >> 4;
        int n = nb * 160 + nl;
        int g = (n >> 4) % 5;
        int u = (n / 80) * 16 + (n & 15);
        int c = (g < 4) ? g * 256 + u : 256 + u;
        bf16x8 hv, lv;
        #pragma unroll
        for (int j = 0; j < 8; j++) {
            int kl = q * 4 + (j & 3) + ((j >> 2) << 4);
            int k = kc * 32 + kl;
            const float* s;
            if (k < 256) s = W + k * 1024 + c;
            else         s = ((g < 4) ? U : Un) + (k - 256) * 1024 + c;
            float x = *s;
            short h = f2bf(x);
            hv[j] = h;
            lv[j] = f2bf(x - bf2f(h));
        }
        int off = (((nl * 64 + q * 16) ^ ((nl & 7) << 4)) >> 1);  // shorts
        short* dst = Bg + (long)(nb * 16 + kc) * 10240 + off;
        *(bf16x8*)dst = hv;
        *(bf16x8*)(dst + 5120) = lv;
    } else if (blk < 8512) {
        // coef: per-batch alpha/beta, one wave per b
        int lane = tid & 63;
        int wid  = tid >> 6;
        int b = (blk - 4416) * 4 + wid;
        int t = timep[0];
        int p = revmap[b * TT + t];
        int ng = neighbors[(b * TT + p) * MM + lane];
        int mp = mapping[b * MM + lane];
        int cnt = ng;
        int cp  = (mp < t) ? ng : 0;
        #pragma unroll
        for (int off = 32; off > 0; off >>= 1) {
            cnt += __shfl_xor(cnt, off);
            cp  += __shfl_xor(cp, off);
        }
        if (lane == 0) {
            float a = 0.f, be = 0.f;
            if (cnt > 0) {
                float inv = 1.0f / (float)cnt;
                a  = (float)cp * inv;
                be = (float)(cnt - cp) * inv;
            }
            alpha[b] = a;
            beta[b]  = be;
        }
    } else {
        // colsum partials: block p sums 128 rows of h1/h2 -> part[p][256]
        int p = blk - 8512;        // 0..127
        int r0 = p * 128;
        float s1 = 0.f, s2 = 0.f;
        for (int r = 0; r < 128; r++) {
            s1 += h1[(r0 + r) * UU + tid];
            s2 += h2[(r0 + r) * UU + tid];
        }
        part1[p * 256 + tid] = s1;
        part2[p * 256 + tid] = s2;
    }
}

// ---- D2: reduce partials -> hs (LDS); v1 = hs1@Un, v2 = hs2@Un; zero m1/m2 ----
__global__ void k_mid(const float* __restrict__ Un,
                      const float* __restrict__ part1, const float* __restrict__ part2,
                      float* __restrict__ v1, float* __restrict__ v2,
                      float* __restrict__ m12) {
    __shared__ float sh1[256], sh2[256];
    int tid = threadIdx.x;
    if (blockIdx.x == 0 && tid < 512) m12[tid] = 0.f;   // zero m1,m2 (contiguous)
    float s1 = 0.f, s2 = 0.f;
    #pragma unroll 8
    for (int p = 0; p < 128; p++) {
        s1 += part1[p * 256 + tid];
        s2 += part2[p * 256 + tid];
    }
    sh1[tid] = s1;
    sh2[tid] = s2;
    __syncthreads();
    int j = blockIdx.x * 256 + tid;   // 4 blocks -> j 0..1023
    float a1 = 0.f, a2 = 0.f;
    for (int k = 0; k < 256; k++) {
        float w = Un[k * 1024 + j];
        a1 = fmaf(sh1[k], w, a1);
        a2 = fmaf(sh2[k], w, a2);
    }
    v1[j] = a1;
    v2[j] = a2;
}

// ---- D3: MFMA GEMM + fused LSTM epilogue, A register-double-buffered ----
// grid (128 mb, 8 nb), 256 threads = 4 waves; wave tile 32x160 (2 M x 10 N frags)
#define STAGE_B(KC, BUF) { \
    const char* _s = (const char*)(Bt + (long)(KC) * 10240); \
    char* _d = (char*)(&Bs[BUF][0]); \
    _Pragma("unroll") \
    for (int _c = 0; _c < 5; _c++) { \
        int _u = wv * 5120 + _c * 1024; \
        __builtin_amdgcn_global_load_lds( \
            (const __attribute__((address_space(1))) void*)(_s + _u + lane * 16), \
            (__attribute__((address_space(3))) void*)(_d + _u), 16, 0, 0); \
    } }

__global__ __launch_bounds__(256) void k_gemm_mfma(
    const short* __restrict__ Ahi, const short* __restrict__ Alo,
    const short* __restrict__ Bg,
    const float* __restrict__ c1p, const float* __restrict__ c2p,
    const float* __restrict__ bias,
    const float* __restrict__ alpha, const float* __restrict__ beta,
    const float* __restrict__ v1, const float* __restrict__ v2,
    float* __restrict__ m1, float* __restrict__ m2,
    float* __restrict__ out_h, float* __restrict__ out_mem)
{
    __shared__ short Bs[2][10240];   // 2 x 20 KB

    const int tid = threadIdx.x;
    const int lane = tid & 63;
    const int wv = tid >> 6;
    const int mb = blockIdx.x;
    const int nb = blockIdx.y;
    const int m0 = mb * 128;
    const short* Bt = Bg + (long)nb * 163840;

    const int uloc = lane & 15;
    const int rgrp = lane >> 4;
    const int aoff = (m0 + wv * 32 + uloc) * 32 + rgrp * 8;
    const int bbase = ((uloc * 64 + rgrp * 16) ^ ((lane & 7) << 4));

    f32x4 acc[2][10];
    #pragma unroll
    for (int i = 0; i < 2; i++)
        #pragma unroll
        for (int j = 0; j < 10; j++) acc[i][j] = (f32x4){0.f, 0.f, 0.f, 0.f};

    STAGE_B(0, 0);
    bf16x8 ah0 = *(const bf16x8*)(Ahi + aoff);
    bf16x8 ah1 = *(const bf16x8*)(Ahi + aoff + 512);
    bf16x8 al0 = *(const bf16x8*)(Alo + aoff);
    bf16x8 al1 = *(const bf16x8*)(Alo + aoff + 512);

    for (int kc = 0; kc < 16; kc++) {
        __syncthreads();                         // B(kc) staged; A(kc) in regs
        bf16x8 nh0, nh1, nl0, nl1;
        if (kc + 1 < 16) {
            STAGE_B(kc + 1, (kc + 1) & 1);
            long ab = (long)(kc + 1) * 524288 + aoff;   // prefetch A(kc+1)
            nh0 = *(const bf16x8*)(Ahi + ab);
            nh1 = *(const bf16x8*)(Ahi + ab + 512);
            nl0 = *(const bf16x8*)(Alo + ab);
            nl1 = *(const bf16x8*)(Alo + ab + 512);
        }

        const char* bp = (const char*)Bs + (kc & 1) * 20480 + bbase;
        #pragma unroll
        for (int nf = 0; nf < 10; nf++) {
            bf16x8 bh = *(const bf16x8*)(bp + nf * 1024);
            bf16x8 bl = *(const bf16x8*)(bp + 10240 + nf * 1024);
            acc[0][nf] = __builtin_amdgcn_mfma_f32_16x16x32_bf16(ah0, bh, acc[0][nf], 0, 0, 0);
            acc[1][nf] = __builtin_amdgcn_mfma_f32_16x16x32_bf16(ah1, bh, acc[1][nf], 0, 0, 0);
            acc[0][nf] = __builtin_amdgcn_mfma_f32_16x16x32_bf16(al0, bh, acc[0][nf], 0, 0, 0);
            acc[1][nf] = __builtin_amdgcn_mfma_f32_16x16x32_bf16(al1, bh, acc[1][nf], 0, 0, 0);
            acc[0][nf] = __builtin_amdgcn_mfma_f32_16x16x32_bf16(ah0, bl, acc[0][nf], 0, 0, 0);
            acc[1][nf] = __builtin_amdgcn_mfma_f32_16x16x32_bf16(ah1, bl, acc[1][nf], 0, 0, 0);
        }
        if (kc + 1 < 16) { ah0 = nh0; ah1 = nh1; al0 = nl0; al1 = nl1; }
    }

    // ---- fused epilogue; C/D frag: col=lane&15 (unit), row=(lane>>4)*4+reg ----
    float pm1[2] = {0.f, 0.f}, pm2[2] = {0.f, 0.f};
    #pragma unroll
    for (int ub = 0; ub < 2; ub++) {
        int u = nb * 32 + ub * 16 + uloc;
        float bi = bias[u], bfv = bias[256 + u], bc = bias[512 + u], bo = bias[768 + u];
        float v1i = v1[u], v1c = v1[512 + u], v1o = v1[768 + u];
        float v2i = v2[u], v2c = v2[512 + u], v2o = v2[768 + u];
        #pragma unroll
        for (int mf = 0; mf < 2; mf++) {
            int bb = m0 + wv * 32 + mf * 16 + rgrp * 4;
            f32x4 fi = acc[mf][ub * 5 + 0];
            f32x4 ff = acc[mf][ub * 5 + 1];
            f32x4 fc = acc[mf][ub * 5 + 2];
            f32x4 fo = acc[mf][ub * 5 + 3];
            f32x4 fa = acc[mf][ub * 5 + 4];
            #pragma unroll
            for (int r = 0; r < 4; r++) {
                int b = bb + r;
                float al = alpha[b], be = beta[b];
                float c1 = c1p[b * 256 + u];
                float c2 = c2p[b * 256 + u];
                float zi  = fi[r] + bi + al * v1i + be * v2i;
                float zf  = ff[r] + bfv;
                float zc  = fc[r] + bc + al * v1c + be * v2c;
                float zo  = fo[r] + bo + al * v1o + be * v2o;
                float zfa = fa[r] + bfv;
                float ig = hsig(zi), fg = hsig(zf), og = hsig(zo), fav = hsig(zfa);
                float cg = tanhf(zc);
                out_mem[b * 256 + u] = fg * c1 + ig * cg;
                out_h[b * 256 + u]  = og;
                pm1[ub] += fav * c1;
                pm2[ub] += fav * c2;
            }
        }
    }

    #pragma unroll
    for (int ub = 0; ub < 2; ub++) {
        pm1[ub] += __shfl_xor(pm1[ub], 16); pm1[ub] += __shfl_xor(pm1[ub], 32);
        pm2[ub] += __shfl_xor(pm2[ub], 16); pm2[ub] += __shfl_xor(pm2[ub], 32);
    }
    __syncthreads();
    float* red = (float*)&Bs[0][0];
    if (rgrp == 0) {
        #pragma unroll
        for (int ub = 0; ub < 2; ub++) {
            red[((wv * 2 + 0) * 2 + ub) * 16 + uloc] = pm1[ub];
            red[((wv * 2 + 1) * 2 + ub) * 16 + uloc] = pm2[ub];
        }
    }
    __syncthreads();
    if (tid < 64) {
        int d = tid >> 5, ub = (tid >> 4) & 1, ui = tid & 15;
        float s = 0.f;
        #pragma unroll
        for (int w = 0; w < 4; w++) s += red[((w * 2 + d) * 2 + ub) * 16 + ui];
        atomicAdd(((d == 0) ? m1 : m2) + nb * 32 + ub * 16 + ui, s);
    }
}

// ---- D4: memory = alpha*m1 + beta*m2 + mem_partial ; h = o * tanh(memory) ----
__global__ void k_final(const float* __restrict__ alpha, const float* __restrict__ beta,
                        const float* __restrict__ m1, const float* __restrict__ m2,
                        float* __restrict__ out_h, float* __restrict__ out_mem) {
    int idx = blockIdx.x * 256 + threadIdx.x;
    int b  = idx >> 6;
    int uv = idx & 63;
    float4 mp = ((const float4*)out_mem)[idx];
    float4 ov = ((const float4*)out_h)[idx];
    float al = alpha[b], be = beta[b];
    float4 m1v = ((const float4*)m1)[uv];
    float4 m2v = ((const float4*)m2)[uv];
    float4 mem, h;
    mem.x = fmaf(al, m1v.x, fmaf(be, m2v.x, mp.x)); h.x = ov.x * tanhf(mem.x);
    mem.y = fmaf(al, m1v.y, fmaf(be, m2v.y, mp.y)); h.y = ov.y * tanhf(mem.y);
    mem.z = fmaf(al, m1v.z, fmaf(be, m2v.z, mp.z)); h.z = ov.z * tanhf(mem.z);
    mem.w = fmaf(al, m1v.w, fmaf(be, m2v.w, mp.w)); h.w = ov.w * tanhf(mem.w);
    ((float4*)out_mem)[idx] = mem;
    ((float4*)out_h)[idx]   = h;
}

extern "C" void kernel_launch(void* const* d_in, const int* in_sizes, int n_in,
                              void* d_out, int out_size, void* d_ws, size_t ws_size,
                              hipStream_t stream) {
    const float* inputs   = (const float*)d_in[0];
    const float* h_tm1    = (const float*)d_in[1];
    const float* c_tm1    = (const float*)d_in[2];
    const float* h_tm2    = (const float*)d_in[3];
    const float* c_tm2    = (const float*)d_in[4];
    const int*   neighbors= (const int*)d_in[5];
    const int*   mapping  = (const int*)d_in[6];
    const int*   revmap   = (const int*)d_in[7];
    const int*   timep    = (const int*)d_in[8];
    const float* W        = (const float*)d_in[9];
    const float* Uw       = (const float*)d_in[10];
    const float* Un       = (const float*)d_in[11];
    const float* bias     = (const float*)d_in[12];

    float* ws    = (float*)d_ws;
    float* alpha = ws + WS_ALPHA;
    float* beta  = ws + WS_BETA;
    float* m1    = ws + WS_M1;
    float* m2    = ws + WS_M2;
    float* v1    = ws + WS_V1;
    float* v2    = ws + WS_V2;
    float* part1 = ws + WS_PART1;
    float* part2 = ws + WS_PART2;

    short* Ahi = (short*)((char*)d_ws + WS_BF16_BYTE);
    short* Alo = Ahi + 8388608;
    short* Bg  = Alo + 8388608;

    float* out_h   = (float*)d_out;
    float* out_mem = out_h + BB * UU;

    k_prep<<<8640, 256, 0, stream>>>(inputs, h_tm1, h_tm2, neighbors, mapping, revmap,
                                     timep, W, Uw, Un, Ahi, Alo, Bg, alpha, beta,
                                     part1, part2);
    k_mid<<<4, 256, 0, stream>>>(Un, part1, part2, v1, v2, m1);

    dim3 g3(128, 8);
    k_gemm_mfma<<<g3, 256, 0, stream>>>(Ahi, Alo, Bg, c_tm1, c_tm2, bias,
                                        alpha, beta, v1, v2, m1, m2, out_h, out_mem);

    k_final<<<BB * UU / 4 / 256, 256, 0, stream>>>(alpha, beta, m1, m2, out_h, out_mem);
}